// Round 2
// baseline (598.949 us; speedup 1.0000x reference)
//
#include <hip/hip_runtime.h>
#include <hip/hip_bf16.h>
#include <stdint.h>

typedef __attribute__((ext_vector_type(8))) short bv8;   // 8 x bf16 (MFMA A/B frag)
typedef __attribute__((ext_vector_type(4))) short sv4;   // 4 x bf16
typedef __attribute__((ext_vector_type(4))) float f4;    // MFMA C/D frag

#define LDS_AS __attribute__((address_space(3)))
#define GLB_AS __attribute__((address_space(1)))

#if __has_builtin(__builtin_amdgcn_exp2f)
#define EXP2F(x) __builtin_amdgcn_exp2f(x)
#else
#define EXP2F(x) exp2f(x)
#endif

__device__ __forceinline__ void gload16(const void* g, void* l) {
  // async global->LDS, 16B per lane; LDS dest is wave-uniform base + lane*16
  __builtin_amdgcn_global_load_lds((GLB_AS void*)(g), (LDS_AS void*)(l), 16, 0, 0);
}

__device__ __forceinline__ short f2bs(float x) {
  return __builtin_bit_cast(short, __float2bfloat16(x));
}
__device__ __forceinline__ float bs2f(short s) {
  unsigned u = ((unsigned)(unsigned short)s) << 16;
  return __builtin_bit_cast(float, u);
}

// ---------------- fp32 -> bf16 convert (x) ----------------
__global__ __launch_bounds__(256) void k_cvt(const float* __restrict__ in, short* __restrict__ out) {
  const int i = (blockIdx.x * 256 + threadIdx.x) * 4;
  const float4 v = *(const float4*)(in + i);
  sv4 o; o[0] = f2bs(v.x); o[1] = f2bs(v.y); o[2] = f2bs(v.z); o[3] = f2bs(v.w);
  *(sv4*)(out + i) = o;
}

// ---------------- W [K][N] fp32 -> Wt [N][K] bf16 ----------------
__global__ __launch_bounds__(256) void k_transpose(const float* __restrict__ W, short* __restrict__ Wt,
                                                   int K, int N) {
  __shared__ float tile[32][33];
  const int tx = threadIdx.x & 31, ty = threadIdx.x >> 5;
  const int n0 = blockIdx.x * 32, k0 = blockIdx.y * 32;
#pragma unroll
  for (int i = 0; i < 32; i += 8)
    tile[ty + i][tx] = W[(size_t)(k0 + ty + i) * N + n0 + tx];
  __syncthreads();
#pragma unroll
  for (int i = 0; i < 32; i += 8)
    Wt[(size_t)(n0 + ty + i) * K + k0 + tx] = f2bs(tile[tx][ty + i]);
}

// ---------------- bf16 MFMA GEMM: C[M][N] = A[M][K] @ Bt[N][K]^T + bias ----------------
// EPI: 0 plain bf16 out, 1 relu bf16 out, 2 Q/K out [B,H,S,64], 3 V out [B,H,64,S]
template<int EPI>
__global__ __launch_bounds__(256) void k_gemm(const short* __restrict__ A, const short* __restrict__ Bt,
                                              const float* __restrict__ bias, short* __restrict__ C,
                                              int M, int N, int K) {
  __shared__ __align__(16) short As[128 * 64];
  __shared__ __align__(16) short Bs[128 * 64];
  const int t = threadIdx.x;
  const int lane = t & 63, w = t >> 6;
  const int wm = w >> 1, wn = w & 1;
  const int lr = lane & 15, lg = lane >> 4;
  const int m0 = blockIdx.y * 128, n0 = blockIdx.x * 128;

  f4 acc[4][4] = {};

  for (int k0 = 0; k0 < K; k0 += 64) {
    __syncthreads();
#pragma unroll
    for (int i = 0; i < 4; ++i) {
      const int L = t * 16 + i * 4096;
      const int row = L >> 7;
      const int cbs = (L & 127) ^ ((row & 7) << 4);   // inverse-swizzled global source
      gload16(A + (size_t)(m0 + row) * K + k0 + (cbs >> 1), (char*)As + L);
      gload16(Bt + (size_t)(n0 + row) * K + k0 + (cbs >> 1), (char*)Bs + L);
    }
    __syncthreads();
#pragma unroll
    for (int kk = 0; kk < 2; ++kk) {
      bv8 af[4], bfr[4];
#pragma unroll
      for (int mi = 0; mi < 4; ++mi) {
        const int row = wm * 64 + mi * 16 + lr;
        const int cb = kk * 64 + lg * 16;
        af[mi] = *(const bv8*)((const char*)As + row * 128 + (cb ^ ((row & 7) << 4)));
      }
#pragma unroll
      for (int ni = 0; ni < 4; ++ni) {
        const int row = wn * 64 + ni * 16 + lr;
        const int cb = kk * 64 + lg * 16;
        bfr[ni] = *(const bv8*)((const char*)Bs + row * 128 + (cb ^ ((row & 7) << 4)));
      }
#pragma unroll
      for (int mi = 0; mi < 4; ++mi)
#pragma unroll
        for (int ni = 0; ni < 4; ++ni)
          acc[mi][ni] = __builtin_amdgcn_mfma_f32_16x16x32_bf16(af[mi], bfr[ni], acc[mi][ni], 0, 0, 0);
    }
  }

#pragma unroll
  for (int ni = 0; ni < 4; ++ni) {
    const int c = n0 + wn * 64 + ni * 16 + lr;
    const float bvs = bias[c];
#pragma unroll
    for (int mi = 0; mi < 4; ++mi) {
#pragma unroll
      for (int j = 0; j < 4; ++j) {
        const int r = m0 + wm * 64 + mi * 16 + lg * 4 + j;   // C/D: col=lane&15, row=(lane>>4)*4+reg
        float v = acc[mi][ni][j] + bvs;
        if (EPI == 1) v = fmaxf(v, 0.f);
        size_t off;
        if (EPI == 2) {        // [B,H,S,64]
          const int b = r >> 11, s = r & 2047, h = c >> 6, d = c & 63;
          off = ((size_t)(b * 16 + h) * 2048 + s) * 64 + d;
        } else if (EPI == 3) { // [B,H,64,S]  (V stored transposed for PV B-frags)
          const int b = r >> 11, s = r & 2047, h = c >> 6, d = c & 63;
          off = ((size_t)(b * 16 + h) * 64 + d) * 2048 + s;
        } else {
          off = (size_t)r * N + c;
        }
        C[off] = f2bs(v);
      }
    }
  }
}

// ---------------- flash attention, swapped-operand form ----------------
// per block = (q-tile 128, bh), 4 waves x 32 q-rows. QK^T computed as S^T =
// mfma(K,Q) so q lives on lane&15 and k on the reg axis: softmax is lane-local,
// P writes are b64, PV computes O^T = mfma(V^T, P) keeping q lane-local to the end.
__global__ __launch_bounds__(256, 3) void k_attn(const short* __restrict__ Qg, const short* __restrict__ Kg,
                                                 const short* __restrict__ Vtg, short* __restrict__ Oc) {
  __shared__ __align__(16) short Ks[128 * 64];    // [s][dk] swizzled, 128B rows
  __shared__ __align__(16) short Ps[4][32 * 64];  // per-wave P [q][k-half], 128B rows, swizzled

  const int t = threadIdx.x, lane = t & 63, w = t >> 6;
  const int lr = lane & 15, lg = lane >> 4;
  const int q0 = blockIdx.x * 128;
  const int bh = blockIdx.y;
  const int b = bh >> 4, h = bh & 15;
  const short* Qp = Qg + (size_t)bh * 2048 * 64;
  const short* Kp = Kg + (size_t)bh * 2048 * 64;
  const short* Vp = Vtg + (size_t)bh * 64 * 2048;

  // hoist Q fragments (wave w owns q rows [w*32, w*32+32)); B-frag: col=lr=q, d=lg*8+i
  bv8 qf[2][2];
#pragma unroll
  for (int mi = 0; mi < 2; ++mi)
#pragma unroll
    for (int kk = 0; kk < 2; ++kk)
      qf[mi][kk] = *(const bv8*)(Qp + (size_t)(q0 + w * 32 + mi * 16 + lr) * 64 + kk * 32 + lg * 8);

  f4 Oa[2][4] = {};                     // O^T frags: row=d, col=q(=lr)
  float mrow[2] = {-1e30f, -1e30f};
  float lsum[2] = {0.f, 0.f};
  const float SC = 0.125f * 1.44269504089f;  // (1/sqrt(64)) * log2(e)
  short* Pw = (short*)Ps[w];

  for (int kt = 0; kt < 2048; kt += 128) {
    __syncthreads();
#pragma unroll
    for (int i = 0; i < 4; ++i) {
      const int L = t * 16 + i * 4096;
      const int row = L >> 7;
      const int cbs = (L & 127) ^ ((row & 7) << 4);
      gload16(Kp + (size_t)(kt + row) * 64 + (cbs >> 1), (char*)Ks + L);
    }
    __syncthreads();

    // S^T = K @ Q^T: Sa[mi][ni] rows=k (ni block), cols=q (mi block, on lr)
    f4 Sa[2][8] = {};
    __builtin_amdgcn_s_setprio(1);
#pragma unroll
    for (int kk = 0; kk < 2; ++kk) {
      bv8 kf[8];
#pragma unroll
      for (int ni = 0; ni < 8; ++ni) {
        const int row = ni * 16 + lr;
        const int cb = kk * 64 + lg * 16;
        kf[ni] = *(const bv8*)((const char*)Ks + row * 128 + (cb ^ ((row & 7) << 4)));
      }
#pragma unroll
      for (int mi = 0; mi < 2; ++mi)
#pragma unroll
        for (int ni = 0; ni < 8; ++ni)
          Sa[mi][ni] = __builtin_amdgcn_mfma_f32_16x16x32_bf16(kf[ni], qf[mi][kk], Sa[mi][ni], 0, 0, 0);
    }
    __builtin_amdgcn_s_setprio(0);

    // lane-local online softmax for q-row = mi*16+lr (lane owns 32 of 128 k-vals)
    float scf[2];
#pragma unroll
    for (int mi = 0; mi < 2; ++mi) {
      float pm = Sa[mi][0][0];
#pragma unroll
      for (int ni = 0; ni < 8; ++ni)
#pragma unroll
        for (int j = 0; j < 4; ++j) pm = fmaxf(pm, Sa[mi][ni][j]);
      pm = fmaxf(pm, __shfl_xor(pm, 16));
      pm = fmaxf(pm, __shfl_xor(pm, 32));
      const float mn = fmaxf(mrow[mi], pm);
      scf[mi] = EXP2F((mrow[mi] - mn) * SC);
      mrow[mi] = mn;
      const float nm = -mn * SC;
      float rs = 0.f;
#pragma unroll
      for (int ni = 0; ni < 8; ++ni)
#pragma unroll
        for (int j = 0; j < 4; ++j) {
          const float p = EXP2F(fmaf(Sa[mi][ni][j], SC, nm));
          Sa[mi][ni][j] = p;
          rs += p;
        }
      rs += __shfl_xor(rs, 16);
      rs += __shfl_xor(rs, 32);
      lsum[mi] = lsum[mi] * scf[mi] + rs;
#pragma unroll
      for (int nO = 0; nO < 4; ++nO)
#pragma unroll
        for (int j = 0; j < 4; ++j) Oa[mi][nO][j] *= scf[mi];
    }

    // PV in two k-halves of 64: pack P -> LDS (b64, swizzled), V^T frags direct from L1/L2
#pragma unroll
    for (int hf = 0; hf < 2; ++hf) {
      bv8 vfh[2][4];
#pragma unroll
      for (int k2 = 0; k2 < 2; ++k2)
#pragma unroll
        for (int nO = 0; nO < 4; ++nO)
          vfh[k2][nO] = *(const bv8*)(Vp + (size_t)(nO * 16 + lr) * 2048 + kt + (hf * 2 + k2) * 32 + lg * 8);
#pragma unroll
      for (int mi = 0; mi < 2; ++mi)
#pragma unroll
        for (int nl = 0; nl < 4; ++nl) {
          const int ni = hf * 4 + nl;
          const int q = mi * 16 + lr;
          const int cb = (nl * 32 + lg * 8) ^ ((q & 7) << 4);
          sv4 pk;
          pk[0] = f2bs(Sa[mi][ni][0]); pk[1] = f2bs(Sa[mi][ni][1]);
          pk[2] = f2bs(Sa[mi][ni][2]); pk[3] = f2bs(Sa[mi][ni][3]);
          *(sv4*)((char*)Pw + q * 128 + cb) = pk;
        }
#pragma unroll
      for (int k2 = 0; k2 < 2; ++k2) {
        bv8 pf[2];
#pragma unroll
        for (int mi = 0; mi < 2; ++mi) {
          const int row = mi * 16 + lr;
          const int cb = (k2 * 64 + lg * 16) ^ ((row & 7) << 4);
          pf[mi] = *(const bv8*)((const char*)Pw + row * 128 + cb);
        }
        __builtin_amdgcn_s_setprio(1);
#pragma unroll
        for (int mi = 0; mi < 2; ++mi)
#pragma unroll
          for (int nO = 0; nO < 4; ++nO)
            Oa[mi][nO] = __builtin_amdgcn_mfma_f32_16x16x32_bf16(vfh[k2][nO], pf[mi], Oa[mi][nO], 0, 0, 0);
        __builtin_amdgcn_s_setprio(0);
      }
    }
  }

  // O^T frags: lane holds q = q0+w*32+mi*16+lr, d = nO*16+lg*4+j -> 8B stores
#pragma unroll
  for (int mi = 0; mi < 2; ++mi) {
    const float inv = 1.f / lsum[mi];
    const int q = q0 + w * 32 + mi * 16 + lr;
#pragma unroll
    for (int nO = 0; nO < 4; ++nO) {
      sv4 o;
#pragma unroll
      for (int j = 0; j < 4; ++j) o[j] = f2bs(Oa[mi][nO][j] * inv);
      const int c = h * 64 + nO * 16 + lg * 4;
      *(sv4*)(Oc + ((size_t)b * 2048 + q) * 1024 + c) = o;
    }
  }
}

// ---------------- residual + LayerNorm (mean, unbiased std, eps on std) ----------------
// MODE 0: residual fp32, out bf16.  MODE 1: residual bf16, out fp32.
template<int MODE>
__global__ __launch_bounds__(256) void k_resnorm(const short* __restrict__ a, const void* __restrict__ res,
                                                 const float* __restrict__ alpha, const float* __restrict__ beta,
                                                 void* __restrict__ out) {
  const int row = blockIdx.x;
  const int t = threadIdx.x;
  const int lane = t & 63, w = t >> 6;
  const size_t base = (size_t)row * 1024;

  const sv4 av = *(const sv4*)(a + base + t * 4);
  float v[4];
  if (MODE == 0) {
    const float4 rv = *(const float4*)((const float*)res + base + t * 4);
    v[0] = bs2f(av[0]) + rv.x; v[1] = bs2f(av[1]) + rv.y;
    v[2] = bs2f(av[2]) + rv.z; v[3] = bs2f(av[3]) + rv.w;
  } else {
    const sv4 rv = *(const sv4*)((const short*)res + base + t * 4);
#pragma unroll
    for (int i = 0; i < 4; ++i) v[i] = bs2f(av[i]) + bs2f(rv[i]);
  }
  float s = v[0] + v[1] + v[2] + v[3];
  float sq = v[0] * v[0] + v[1] * v[1] + v[2] * v[2] + v[3] * v[3];
#pragma unroll
  for (int m = 1; m < 64; m <<= 1) { s += __shfl_xor(s, m); sq += __shfl_xor(sq, m); }
  __shared__ float red[8];
  if (lane == 0) { red[w] = s; red[w + 4] = sq; }
  __syncthreads();
  s = red[0] + red[1] + red[2] + red[3];
  sq = red[4] + red[5] + red[6] + red[7];
  const float mean = s * (1.f / 1024.f);
  const float var = (sq - 1024.f * mean * mean) * (1.f / 1023.f);   // ddof=1
  const float inv = 1.f / (sqrtf(fmaxf(var, 0.f)) + 1e-6f);          // eps added to std
  const float4 al = *(const float4*)(alpha + t * 4);
  const float4 be = *(const float4*)(beta + t * 4);
  float y[4];
  y[0] = al.x * (v[0] - mean) * inv + be.x;
  y[1] = al.y * (v[1] - mean) * inv + be.y;
  y[2] = al.z * (v[2] - mean) * inv + be.z;
  y[3] = al.w * (v[3] - mean) * inv + be.w;
  if (MODE == 0) {
    sv4 o; o[0] = f2bs(y[0]); o[1] = f2bs(y[1]); o[2] = f2bs(y[2]); o[3] = f2bs(y[3]);
    *(sv4*)((short*)out + base + t * 4) = o;
  } else {
    *(float4*)((float*)out + base + t * 4) = make_float4(y[0], y[1], y[2], y[3]);
  }
}

extern "C" void kernel_launch(void* const* d_in, const int* in_sizes, int n_in,
                              void* d_out, int out_size, void* d_ws, size_t ws_size,
                              hipStream_t stream) {
  const float* x   = (const float*)d_in[0];
  const float* Wq  = (const float*)d_in[1];
  const float* bq  = (const float*)d_in[2];
  const float* Wk  = (const float*)d_in[3];
  const float* bk  = (const float*)d_in[4];
  const float* Wv  = (const float*)d_in[5];
  const float* bv  = (const float*)d_in[6];
  const float* Wo  = (const float*)d_in[7];
  const float* bo  = (const float*)d_in[8];
  const float* al1 = (const float*)d_in[9];
  const float* bi1 = (const float*)d_in[10];
  const float* al2 = (const float*)d_in[11];
  const float* bi2 = (const float*)d_in[12];
  const float* W1  = (const float*)d_in[13];
  const float* b1  = (const float*)d_in[14];
  const float* W2  = (const float*)d_in[15];
  const float* b2  = (const float*)d_in[16];

  if (ws_size < (size_t)136 * 1024 * 1024) return;  // need 136MB scratch

  char* ws = (char*)d_ws;
  short* xb  = (short*)(ws);                   // 16MB, dead after QKV
  short* Qb  = (short*)(ws + (16ll << 20));    // 16MB
  short* Kb  = (short*)(ws + (32ll << 20));    // 16MB
  short* Vtb = (short*)(ws + (48ll << 20));    // 16MB
  short* Hb  = (short*)(ws);                   // 64MB: reuses xb+Q+K+Vt after attention
  short* Wqt = (short*)(ws + (64ll << 20));
  short* Wkt = (short*)(ws + (66ll << 20));
  short* Wvt = (short*)(ws + (68ll << 20));
  short* Wot = (short*)(ws + (70ll << 20));
  short* W1t = (short*)(ws + (72ll << 20));    // 8MB
  short* W2t = (short*)(ws + (80ll << 20));    // 8MB
  short* Cc  = (short*)(ws + (88ll << 20));    // 16MB
  short* AOb = (short*)(ws + (104ll << 20));   // 16MB, reused for FFb
  short* N1b = (short*)(ws + (120ll << 20));   // 16MB
  short* FFb = (short*)(ws + (104ll << 20));

  // prep: bf16 conversions + weight transposes
  k_cvt<<<8192, 256, 0, stream>>>(x, xb);
  k_transpose<<<dim3(32, 32), 256, 0, stream>>>(Wq, Wqt, 1024, 1024);
  k_transpose<<<dim3(32, 32), 256, 0, stream>>>(Wk, Wkt, 1024, 1024);
  k_transpose<<<dim3(32, 32), 256, 0, stream>>>(Wv, Wvt, 1024, 1024);
  k_transpose<<<dim3(32, 32), 256, 0, stream>>>(Wo, Wot, 1024, 1024);
  k_transpose<<<dim3(128, 32), 256, 0, stream>>>(W1, W1t, 1024, 4096);
  k_transpose<<<dim3(32, 128), 256, 0, stream>>>(W2, W2t, 4096, 1024);

  // QKV projections (epilogue scatters into head layouts)
  k_gemm<2><<<dim3(8, 64), 256, 0, stream>>>(xb, Wqt, bq, Qb, 8192, 1024, 1024);
  k_gemm<2><<<dim3(8, 64), 256, 0, stream>>>(xb, Wkt, bk, Kb, 8192, 1024, 1024);
  k_gemm<3><<<dim3(8, 64), 256, 0, stream>>>(xb, Wvt, bv, Vtb, 8192, 1024, 1024);

  // attention -> concat
  k_attn<<<dim3(16, 64), 256, 0, stream>>>(Qb, Kb, Vtb, Cc);

  // output proj + LN1
  k_gemm<0><<<dim3(8, 64), 256, 0, stream>>>(Cc, Wot, bo, AOb, 8192, 1024, 1024);
  k_resnorm<0><<<8192, 256, 0, stream>>>(AOb, x, al1, bi1, N1b);

  // FFN + LN2 -> d_out (fp32)
  k_gemm<1><<<dim3(32, 64), 256, 0, stream>>>(N1b, W1t, b1, Hb, 8192, 4096, 1024);
  k_gemm<0><<<dim3(8, 64), 256, 0, stream>>>(Hb, W2t, b2, FFb, 8192, 1024, 4096);
  k_resnorm<1><<<8192, 256, 0, stream>>>(FFb, N1b, al2, bi2, (float*)d_out);
}

// Round 3
// 470.877 us; speedup vs baseline: 1.2720x; 1.2720x over previous
//
#include <hip/hip_runtime.h>
#include <hip/hip_bf16.h>
#include <stdint.h>

typedef __attribute__((ext_vector_type(8))) short bv8;   // 8 x bf16 (MFMA A/B frag)
typedef __attribute__((ext_vector_type(4))) short sv4;   // 4 x bf16
typedef __attribute__((ext_vector_type(4))) float f4;    // MFMA C/D frag

#define LDS_AS __attribute__((address_space(3)))
#define GLB_AS __attribute__((address_space(1)))

#if __has_builtin(__builtin_amdgcn_exp2f)
#define EXP2F(x) __builtin_amdgcn_exp2f(x)
#else
#define EXP2F(x) exp2f(x)
#endif

__device__ __forceinline__ void gload16(const void* g, void* l) {
  // async global->LDS, 16B per lane; LDS dest is wave-uniform base + lane*16
  __builtin_amdgcn_global_load_lds((GLB_AS void*)(g), (LDS_AS void*)(l), 16, 0, 0);
}

__device__ __forceinline__ short f2bs(float x) {
  return __builtin_bit_cast(short, __float2bfloat16(x));
}
__device__ __forceinline__ float bs2f(short s) {
  unsigned u = ((unsigned)(unsigned short)s) << 16;
  return __builtin_bit_cast(float, u);
}

// ---------------- fp32 -> bf16 convert (x) ----------------
__global__ __launch_bounds__(256) void k_cvt(const float* __restrict__ in, short* __restrict__ out) {
  const int i = (blockIdx.x * 256 + threadIdx.x) * 4;
  const float4 v = *(const float4*)(in + i);
  sv4 o; o[0] = f2bs(v.x); o[1] = f2bs(v.y); o[2] = f2bs(v.z); o[3] = f2bs(v.w);
  *(sv4*)(out + i) = o;
}

// ---------------- W [K][N] fp32 -> Wt [N][K] bf16 ----------------
__global__ __launch_bounds__(256) void k_transpose(const float* __restrict__ W, short* __restrict__ Wt,
                                                   int K, int N) {
  __shared__ float tile[32][33];
  const int tx = threadIdx.x & 31, ty = threadIdx.x >> 5;
  const int n0 = blockIdx.x * 32, k0 = blockIdx.y * 32;
#pragma unroll
  for (int i = 0; i < 32; i += 8)
    tile[ty + i][tx] = W[(size_t)(k0 + ty + i) * N + n0 + tx];
  __syncthreads();
#pragma unroll
  for (int i = 0; i < 32; i += 8)
    Wt[(size_t)(n0 + ty + i) * K + k0 + tx] = f2bs(tile[tx][ty + i]);
}

// ---------------- bf16 MFMA GEMM: C[M][N] = A[M][K] @ Bt[N][K]^T + bias ----------------
// EPI: 0 plain bf16 out, 1 relu bf16 out, 2 Q/K out [B,H,S,64], 3 V out [B,H,64,S]
template<int EPI>
__global__ __launch_bounds__(256) void k_gemm(const short* __restrict__ A, const short* __restrict__ Bt,
                                              const float* __restrict__ bias, short* __restrict__ C,
                                              int M, int N, int K) {
  __shared__ __align__(16) short As[128 * 64];
  __shared__ __align__(16) short Bs[128 * 64];
  const int t = threadIdx.x;
  const int lane = t & 63, w = t >> 6;
  const int wm = w >> 1, wn = w & 1;
  const int lr = lane & 15, lg = lane >> 4;
  const int m0 = blockIdx.y * 128, n0 = blockIdx.x * 128;

  f4 acc[4][4] = {};

  for (int k0 = 0; k0 < K; k0 += 64) {
    __syncthreads();
#pragma unroll
    for (int i = 0; i < 4; ++i) {
      const int L = t * 16 + i * 4096;
      const int row = L >> 7;
      const int cbs = (L & 127) ^ ((row & 7) << 4);   // inverse-swizzled global source
      gload16(A + (size_t)(m0 + row) * K + k0 + (cbs >> 1), (char*)As + L);
      gload16(Bt + (size_t)(n0 + row) * K + k0 + (cbs >> 1), (char*)Bs + L);
    }
    __syncthreads();
#pragma unroll
    for (int kk = 0; kk < 2; ++kk) {
      bv8 af[4], bfr[4];
#pragma unroll
      for (int mi = 0; mi < 4; ++mi) {
        const int row = wm * 64 + mi * 16 + lr;
        const int cb = kk * 64 + lg * 16;
        af[mi] = *(const bv8*)((const char*)As + row * 128 + (cb ^ ((row & 7) << 4)));
      }
#pragma unroll
      for (int ni = 0; ni < 4; ++ni) {
        const int row = wn * 64 + ni * 16 + lr;
        const int cb = kk * 64 + lg * 16;
        bfr[ni] = *(const bv8*)((const char*)Bs + row * 128 + (cb ^ ((row & 7) << 4)));
      }
#pragma unroll
      for (int mi = 0; mi < 4; ++mi)
#pragma unroll
        for (int ni = 0; ni < 4; ++ni)
          acc[mi][ni] = __builtin_amdgcn_mfma_f32_16x16x32_bf16(af[mi], bfr[ni], acc[mi][ni], 0, 0, 0);
    }
  }

#pragma unroll
  for (int ni = 0; ni < 4; ++ni) {
    const int c = n0 + wn * 64 + ni * 16 + lr;
    const float bvs = bias[c];
#pragma unroll
    for (int mi = 0; mi < 4; ++mi) {
#pragma unroll
      for (int j = 0; j < 4; ++j) {
        const int r = m0 + wm * 64 + mi * 16 + lg * 4 + j;   // C/D: col=lane&15, row=(lane>>4)*4+reg
        float v = acc[mi][ni][j] + bvs;
        if (EPI == 1) v = fmaxf(v, 0.f);
        size_t off;
        if (EPI == 2) {        // [B,H,S,64]
          const int b = r >> 11, s = r & 2047, h = c >> 6, d = c & 63;
          off = ((size_t)(b * 16 + h) * 2048 + s) * 64 + d;
        } else if (EPI == 3) { // [B,H,64,S]  (V stored transposed for PV A-frags)
          const int b = r >> 11, s = r & 2047, h = c >> 6, d = c & 63;
          off = ((size_t)(b * 16 + h) * 64 + d) * 2048 + s;
        } else {
          off = (size_t)r * N + c;
        }
        C[off] = f2bs(v);
      }
    }
  }
}

// ---------------- flash attention, swapped-operand form, 64-k online steps ----------------
// per block = (q-tile 128, bh), 4 waves x 32 q-rows. S^T = mfma(K,Q): q on lane&15,
// k on reg axis -> lane-local softmax, b64 P writes, O^T = mfma(V^T, P).
// K tile (128x64) staged via global_load_lds; processed as two 64-k halves so only
// Sa[2][4] (32 VGPRs) is live at once -> no spill. XCD swizzle: 8 bh per XCD.
__global__ __launch_bounds__(256) void k_attn(const short* __restrict__ Qg, const short* __restrict__ Kg,
                                              const short* __restrict__ Vtg, short* __restrict__ Oc) {
  __shared__ __align__(16) short Ks[128 * 64];    // [s][dk] swizzled, 128B rows
  __shared__ __align__(16) short Ps[4][32 * 64];  // per-wave P [q][k-half], 128B rows, swizzled

  const int t = threadIdx.x, lane = t & 63, w = t >> 6;
  const int lr = lane & 15, lg = lane >> 4;
  // XCD-aware swizzle: 1024 blocks, chunk=128 -> XCD i owns bh [8i, 8i+8)
  const int bid = blockIdx.x;
  const int wid = (bid & 7) * 128 + (bid >> 3);
  const int q0 = (wid & 15) * 128;
  const int bh = wid >> 4;
  const int b = bh >> 4, h = bh & 15;
  const short* Qp = Qg + (size_t)bh * 2048 * 64;
  const short* Kp = Kg + (size_t)bh * 2048 * 64;
  const short* Vp = Vtg + (size_t)bh * 64 * 2048;

  // hoist Q fragments (wave w owns q rows [w*32, w*32+32)); B-frag: col=lr=q, k=kk*32+lg*8+i
  bv8 qf[2][2];
#pragma unroll
  for (int mi = 0; mi < 2; ++mi)
#pragma unroll
    for (int kk = 0; kk < 2; ++kk)
      qf[mi][kk] = *(const bv8*)(Qp + (size_t)(q0 + w * 32 + mi * 16 + lr) * 64 + kk * 32 + lg * 8);

  f4 Oa[2][4] = {};                     // O^T frags: row=d, col=q(=lr)
  float mrow[2] = {-1e30f, -1e30f};
  float lsum[2] = {0.f, 0.f};
  const float SC = 0.125f * 1.44269504089f;  // (1/sqrt(64)) * log2(e)
  short* Pw = (short*)Ps[w];

  for (int kt = 0; kt < 2048; kt += 128) {
    __syncthreads();
#pragma unroll
    for (int i = 0; i < 4; ++i) {
      const int L = t * 16 + i * 4096;
      const int row = L >> 7;
      const int cbs = (L & 127) ^ ((row & 7) << 4);
      gload16(Kp + (size_t)(kt + row) * 64 + (cbs >> 1), (char*)Ks + L);
    }
    __syncthreads();

#pragma unroll
    for (int hf = 0; hf < 2; ++hf) {
      // S^T over a 64-k half: Sa[mi][nl] rows=k (nl block), cols=q (mi block, on lr)
      f4 Sa[2][4] = {};
      __builtin_amdgcn_s_setprio(1);
#pragma unroll
      for (int kk = 0; kk < 2; ++kk) {
        bv8 kf[4];
#pragma unroll
        for (int nl = 0; nl < 4; ++nl) {
          const int row = (hf * 4 + nl) * 16 + lr;
          const int cb = kk * 64 + lg * 16;
          kf[nl] = *(const bv8*)((const char*)Ks + row * 128 + (cb ^ ((row & 7) << 4)));
        }
#pragma unroll
        for (int mi = 0; mi < 2; ++mi)
#pragma unroll
          for (int nl = 0; nl < 4; ++nl)
            Sa[mi][nl] = __builtin_amdgcn_mfma_f32_16x16x32_bf16(kf[nl], qf[mi][kk], Sa[mi][nl], 0, 0, 0);
      }
      __builtin_amdgcn_s_setprio(0);

      // lane-local online softmax for q-row = mi*16+lr (lane owns 16 of 64 k-vals)
#pragma unroll
      for (int mi = 0; mi < 2; ++mi) {
        float pm = Sa[mi][0][0];
#pragma unroll
        for (int nl = 0; nl < 4; ++nl)
#pragma unroll
          for (int j = 0; j < 4; ++j) pm = fmaxf(pm, Sa[mi][nl][j]);
        pm = fmaxf(pm, __shfl_xor(pm, 16));
        pm = fmaxf(pm, __shfl_xor(pm, 32));
        const float mn = fmaxf(mrow[mi], pm);
        const float scf = EXP2F((mrow[mi] - mn) * SC);
        mrow[mi] = mn;
        const float nm = -mn * SC;
        float rs = 0.f;
#pragma unroll
        for (int nl = 0; nl < 4; ++nl)
#pragma unroll
          for (int j = 0; j < 4; ++j) {
            const float p = EXP2F(fmaf(Sa[mi][nl][j], SC, nm));
            Sa[mi][nl][j] = p;
            rs += p;
          }
        rs += __shfl_xor(rs, 16);
        rs += __shfl_xor(rs, 32);
        lsum[mi] = lsum[mi] * scf + rs;
#pragma unroll
        for (int nO = 0; nO < 4; ++nO)
#pragma unroll
          for (int j = 0; j < 4; ++j) Oa[mi][nO][j] *= scf;
      }

      // pack P -> per-wave LDS (b64 swizzled writes)
#pragma unroll
      for (int mi = 0; mi < 2; ++mi)
#pragma unroll
        for (int nl = 0; nl < 4; ++nl) {
          const int q = mi * 16 + lr;
          const int cb = (nl * 32 + lg * 8) ^ ((q & 7) << 4);
          sv4 pk;
          pk[0] = f2bs(Sa[mi][nl][0]); pk[1] = f2bs(Sa[mi][nl][1]);
          pk[2] = f2bs(Sa[mi][nl][2]); pk[3] = f2bs(Sa[mi][nl][3]);
          *(sv4*)((char*)Pw + q * 128 + cb) = pk;
        }

      // PV: O^T += V^T(frag A, direct from L1/L2) @ P(frag B from LDS)
#pragma unroll
      for (int k2 = 0; k2 < 2; ++k2) {
        bv8 vf[4], pf[2];
#pragma unroll
        for (int nO = 0; nO < 4; ++nO)
          vf[nO] = *(const bv8*)(Vp + (size_t)(nO * 16 + lr) * 2048 + kt + hf * 64 + k2 * 32 + lg * 8);
#pragma unroll
        for (int mi = 0; mi < 2; ++mi) {
          const int row = mi * 16 + lr;
          const int cb = (k2 * 64 + lg * 16) ^ ((row & 7) << 4);
          pf[mi] = *(const bv8*)((const char*)Pw + row * 128 + cb);
        }
        __builtin_amdgcn_s_setprio(1);
#pragma unroll
        for (int mi = 0; mi < 2; ++mi)
#pragma unroll
          for (int nO = 0; nO < 4; ++nO)
            Oa[mi][nO] = __builtin_amdgcn_mfma_f32_16x16x32_bf16(vf[nO], pf[mi], Oa[mi][nO], 0, 0, 0);
        __builtin_amdgcn_s_setprio(0);
      }
    }
  }

  // O^T frags: lane holds q = q0+w*32+mi*16+lr, d = nO*16+lg*4+j -> 8B stores
#pragma unroll
  for (int mi = 0; mi < 2; ++mi) {
    const float inv = 1.f / lsum[mi];
    const int q = q0 + w * 32 + mi * 16 + lr;
#pragma unroll
    for (int nO = 0; nO < 4; ++nO) {
      sv4 o;
#pragma unroll
      for (int j = 0; j < 4; ++j) o[j] = f2bs(Oa[mi][nO][j] * inv);
      const int c = h * 64 + nO * 16 + lg * 4;
      *(sv4*)(Oc + ((size_t)b * 2048 + q) * 1024 + c) = o;
    }
  }
}

// ---------------- residual + LayerNorm (mean, unbiased std, eps on std) ----------------
// MODE 0: residual fp32, out bf16.  MODE 1: residual bf16, out fp32.
template<int MODE>
__global__ __launch_bounds__(256) void k_resnorm(const short* __restrict__ a, const void* __restrict__ res,
                                                 const float* __restrict__ alpha, const float* __restrict__ beta,
                                                 void* __restrict__ out) {
  const int row = blockIdx.x;
  const int t = threadIdx.x;
  const int lane = t & 63, w = t >> 6;
  const size_t base = (size_t)row * 1024;

  const sv4 av = *(const sv4*)(a + base + t * 4);
  float v[4];
  if (MODE == 0) {
    const float4 rv = *(const float4*)((const float*)res + base + t * 4);
    v[0] = bs2f(av[0]) + rv.x; v[1] = bs2f(av[1]) + rv.y;
    v[2] = bs2f(av[2]) + rv.z; v[3] = bs2f(av[3]) + rv.w;
  } else {
    const sv4 rv = *(const sv4*)((const short*)res + base + t * 4);
#pragma unroll
    for (int i = 0; i < 4; ++i) v[i] = bs2f(av[i]) + bs2f(rv[i]);
  }
  float s = v[0] + v[1] + v[2] + v[3];
  float sq = v[0] * v[0] + v[1] * v[1] + v[2] * v[2] + v[3] * v[3];
#pragma unroll
  for (int m = 1; m < 64; m <<= 1) { s += __shfl_xor(s, m); sq += __shfl_xor(sq, m); }
  __shared__ float red[8];
  if (lane == 0) { red[w] = s; red[w + 4] = sq; }
  __syncthreads();
  s = red[0] + red[1] + red[2] + red[3];
  sq = red[4] + red[5] + red[6] + red[7];
  const float mean = s * (1.f / 1024.f);
  const float var = (sq - 1024.f * mean * mean) * (1.f / 1023.f);   // ddof=1
  const float inv = 1.f / (sqrtf(fmaxf(var, 0.f)) + 1e-6f);          // eps added to std
  const float4 al = *(const float4*)(alpha + t * 4);
  const float4 be = *(const float4*)(beta + t * 4);
  float y[4];
  y[0] = al.x * (v[0] - mean) * inv + be.x;
  y[1] = al.y * (v[1] - mean) * inv + be.y;
  y[2] = al.z * (v[2] - mean) * inv + be.z;
  y[3] = al.w * (v[3] - mean) * inv + be.w;
  if (MODE == 0) {
    sv4 o; o[0] = f2bs(y[0]); o[1] = f2bs(y[1]); o[2] = f2bs(y[2]); o[3] = f2bs(y[3]);
    *(sv4*)((short*)out + base + t * 4) = o;
  } else {
    *(float4*)((float*)out + base + t * 4) = make_float4(y[0], y[1], y[2], y[3]);
  }
}

extern "C" void kernel_launch(void* const* d_in, const int* in_sizes, int n_in,
                              void* d_out, int out_size, void* d_ws, size_t ws_size,
                              hipStream_t stream) {
  const float* x   = (const float*)d_in[0];
  const float* Wq  = (const float*)d_in[1];
  const float* bq  = (const float*)d_in[2];
  const float* Wk  = (const float*)d_in[3];
  const float* bk  = (const float*)d_in[4];
  const float* Wv  = (const float*)d_in[5];
  const float* bv  = (const float*)d_in[6];
  const float* Wo  = (const float*)d_in[7];
  const float* bo  = (const float*)d_in[8];
  const float* al1 = (const float*)d_in[9];
  const float* bi1 = (const float*)d_in[10];
  const float* al2 = (const float*)d_in[11];
  const float* bi2 = (const float*)d_in[12];
  const float* W1  = (const float*)d_in[13];
  const float* b1  = (const float*)d_in[14];
  const float* W2  = (const float*)d_in[15];
  const float* b2  = (const float*)d_in[16];

  if (ws_size < (size_t)136 * 1024 * 1024) return;  // need 136MB scratch

  char* ws = (char*)d_ws;
  short* xb  = (short*)(ws);                   // 16MB, dead after QKV
  short* Qb  = (short*)(ws + (16ll << 20));    // 16MB
  short* Kb  = (short*)(ws + (32ll << 20));    // 16MB
  short* Vtb = (short*)(ws + (48ll << 20));    // 16MB
  short* Hb  = (short*)(ws);                   // 64MB: reuses xb+Q+K+Vt after attention
  short* Wqt = (short*)(ws + (64ll << 20));
  short* Wkt = (short*)(ws + (66ll << 20));
  short* Wvt = (short*)(ws + (68ll << 20));
  short* Wot = (short*)(ws + (70ll << 20));
  short* W1t = (short*)(ws + (72ll << 20));    // 8MB
  short* W2t = (short*)(ws + (80ll << 20));    // 8MB
  short* Cc  = (short*)(ws + (88ll << 20));    // 16MB
  short* AOb = (short*)(ws + (104ll << 20));   // 16MB, reused for FFb
  short* N1b = (short*)(ws + (120ll << 20));   // 16MB
  short* FFb = (short*)(ws + (104ll << 20));

  // prep: bf16 conversions + weight transposes
  k_cvt<<<8192, 256, 0, stream>>>(x, xb);
  k_transpose<<<dim3(32, 32), 256, 0, stream>>>(Wq, Wqt, 1024, 1024);
  k_transpose<<<dim3(32, 32), 256, 0, stream>>>(Wk, Wkt, 1024, 1024);
  k_transpose<<<dim3(32, 32), 256, 0, stream>>>(Wv, Wvt, 1024, 1024);
  k_transpose<<<dim3(32, 32), 256, 0, stream>>>(Wo, Wot, 1024, 1024);
  k_transpose<<<dim3(128, 32), 256, 0, stream>>>(W1, W1t, 1024, 4096);
  k_transpose<<<dim3(32, 128), 256, 0, stream>>>(W2, W2t, 4096, 1024);

  // QKV projections (epilogue scatters into head layouts)
  k_gemm<2><<<dim3(8, 64), 256, 0, stream>>>(xb, Wqt, bq, Qb, 8192, 1024, 1024);
  k_gemm<2><<<dim3(8, 64), 256, 0, stream>>>(xb, Wkt, bk, Kb, 8192, 1024, 1024);
  k_gemm<3><<<dim3(8, 64), 256, 0, stream>>>(xb, Wvt, bv, Vtb, 8192, 1024, 1024);

  // attention -> concat (1D grid for XCD swizzle)
  k_attn<<<1024, 256, 0, stream>>>(Qb, Kb, Vtb, Cc);

  // output proj + LN1
  k_gemm<0><<<dim3(8, 64), 256, 0, stream>>>(Cc, Wot, bo, AOb, 8192, 1024, 1024);
  k_resnorm<0><<<8192, 256, 0, stream>>>(AOb, x, al1, bi1, N1b);

  // FFN + LN2 -> d_out (fp32)
  k_gemm<1><<<dim3(32, 64), 256, 0, stream>>>(N1b, W1t, b1, Hb, 8192, 4096, 1024);
  k_gemm<0><<<dim3(8, 64), 256, 0, stream>>>(Hb, W2t, b2, FFb, 8192, 1024, 4096);
  k_resnorm<1><<<8192, 256, 0, stream>>>(FFb, N1b, al2, bi2, (float*)d_out);
}